// Round 2
// baseline (3911.877 us; speedup 1.0000x reference)
//
#include <hip/hip_runtime.h>

// ---------------------------------------------------------------------------
// Transformer (GateLoop-style) forward, MI355X/gfx950.
// Round 2: split-bf16 ("bf16x2") GEMMs everywhere to bisect precision-vs-bug.
//   A = Ah + Al, B = Bh + Bl (each bf16); acc += Ah*Bh + Al*Bh + Ah*Bl
//   -> ~16-bit mantissa accuracy ~= f32 GEMM. Logits GEMM splits A only.
// Everything else (scan, rms, embed, epilogues) unchanged from round 1.
// ---------------------------------------------------------------------------

typedef float fx4 __attribute__((ext_vector_type(4)));
typedef __bf16 bf16x8 __attribute__((ext_vector_type(8)));
typedef unsigned short u16x4 __attribute__((ext_vector_type(4)));

#define AS1 __attribute__((address_space(1)))
#define AS3 __attribute__((address_space(3)))

__device__ __forceinline__ unsigned short f2bf(float f) {
    unsigned u = __float_as_uint(f);
    u += 0x7FFFu + ((u >> 16) & 1u);   // RNE
    return (unsigned short)(u >> 16);
}
__device__ __forceinline__ float bf2f(unsigned short h) {
    return __uint_as_float(((unsigned)h) << 16);
}
__device__ __forceinline__ void split2(float f, unsigned short* hi, unsigned short* lo) {
    unsigned short h = f2bf(f);
    *hi = h;
    *lo = f2bf(f - bf2f(h));
}

// ---------------------------------------------------------------- transpose
// in: f32 [K][N] (batch z) -> hi/lo bf16 [N][K]
__global__ __launch_bounds__(256) void transpose_split_kernel(
    const float* __restrict__ in, unsigned short* __restrict__ hi,
    unsigned short* __restrict__ lo, int K, int N)
{
    __shared__ float tile[32][33];
    const int b = blockIdx.z;
    in += (size_t)b * K * N;
    const size_t obase = (size_t)b * K * N;
    const int k0 = blockIdx.x * 32, n0 = blockIdx.y * 32;
    const int tr = threadIdx.x >> 3;
    const int tc = (threadIdx.x & 7) * 4;
    fx4 v = *(const fx4*)&in[(size_t)(k0 + tr) * N + n0 + tc];
    tile[tr][tc + 0] = v[0]; tile[tr][tc + 1] = v[1];
    tile[tr][tc + 2] = v[2]; tile[tr][tc + 3] = v[3];
    __syncthreads();
    u16x4 oh, ol;
    #pragma unroll
    for (int e = 0; e < 4; ++e) {
        float f = tile[tc + e][tr];
        unsigned short h = f2bf(f);
        oh[e] = h;
        ol[e] = f2bf(f - bf2f(h));
    }
    const size_t oidx = obase + (size_t)(n0 + tr) * K + k0 + tc;
    *(u16x4*)&hi[oidx] = oh;
    if (lo) *(u16x4*)&lo[oidx] = ol;
}

// ---------------------------------------------------------------- embedding
__global__ __launch_bounds__(256) void embed_kernel(
    const int* __restrict__ tokens, const float* __restrict__ emb,
    float* __restrict__ x)
{
    const int row = blockIdx.x;
    const int t = tokens[row];
    const int c = threadIdx.x * 4;
    *(fx4*)&x[(size_t)row * 1024 + c] = *(const fx4*)&emb[(size_t)t * 1024 + c];
}

// ---------------------------------------------------------------- rms -> split bf16
__global__ __launch_bounds__(256) void rms_split_kernel(
    const float* __restrict__ x, const float* __restrict__ g,
    unsigned short* __restrict__ hi, unsigned short* __restrict__ lo)
{
    const int row = blockIdx.x;
    const int c = threadIdx.x * 4;
    fx4 v = *(const fx4*)&x[(size_t)row * 1024 + c];
    float ss = v[0]*v[0] + v[1]*v[1] + v[2]*v[2] + v[3]*v[3];
    #pragma unroll
    for (int off = 32; off > 0; off >>= 1) ss += __shfl_down(ss, off, 64);
    __shared__ float wsum[4];
    if ((threadIdx.x & 63) == 0) wsum[threadIdx.x >> 6] = ss;
    __syncthreads();
    const float nrm = sqrtf(wsum[0] + wsum[1] + wsum[2] + wsum[3]);
    const float scale = 32.0f / fmaxf(nrm, 1e-12f);
    fx4 gg = *(const fx4*)&g[c];
    u16x4 oh, ol;
    #pragma unroll
    for (int e = 0; e < 4; ++e) {
        float f = v[e] * scale * gg[e];
        unsigned short h = f2bf(f);
        oh[e] = h;
        ol[e] = f2bf(f - bf2f(h));
    }
    *(u16x4*)&hi[(size_t)row * 1024 + c] = oh;
    *(u16x4*)&lo[(size_t)row * 1024 + c] = ol;
}

// ---------------------------------------------------------------- gate-loop scan
// One block per (b, h). Brent-Kung in LDS == JAX associative_scan bracketing.
__global__ __launch_bounds__(256) void scan_kernel(
    const float* __restrict__ qkv, const float* __restrict__ al,
    float* __restrict__ y)
{
    const int bh = blockIdx.x;
    const int b = bh >> 10, h = bh & 1023;
    const int tid = threadIdx.x;
    __shared__ float s_re[2048], s_im[2048], s_kv[2048];
    const float* qkv_b = qkv + (size_t)b * 2048 * 3072;
    const float* al_b  = al  + (size_t)b * 2048 * 2048;

    for (int n = tid; n < 2048; n += 256) {
        float kk = qkv_b[(size_t)n * 3072 + 1024 + h];
        float vv = qkv_b[(size_t)n * 3072 + 2048 + h];
        float re = al_b[(size_t)n * 2048 + 2 * h];
        float im = al_b[(size_t)n * 2048 + 2 * h + 1];
        float r = sqrtf(re * re + im * im);
        float sg = 1.0f / (1.0f + expf(-r));
        float a_re, a_im;
        if (r > 0.0f) { float inv = sg / r; a_re = re * inv; a_im = im * inv; }
        else          { a_re = sg; a_im = 0.0f; }
        s_re[n] = a_re; s_im[n] = a_im; s_kv[n] = kk * vv;
    }
    __syncthreads();

    for (int d = 0; d < 11; ++d) {
        const int half = 1 << d, stride = half << 1;
        const int npairs = 2048 >> (d + 1);
        for (int i = tid; i < npairs; i += 256) {
            const int rj = i * stride + stride - 1;
            const int lj = rj - half;
            float lre = s_re[lj], lim = s_im[lj], lkv = s_kv[lj];
            float rre = s_re[rj], rim = s_im[rj], rkv = s_kv[rj];
            s_kv[rj] = rre * lkv + rkv;
            s_re[rj] = rre * lre - rim * lim;
            s_im[rj] = rre * lim + rim * lre;
        }
        __syncthreads();
    }
    for (int d = 9; d >= 0; --d) {
        const int w = 1 << d;
        const int nupd = (2048 >> (d + 1)) - 1;
        for (int t = tid; t < nupd; t += 256) {
            const int i = t + 1;
            const int rj = (2 * i + 1) * w - 1;
            const int lj = 2 * i * w - 1;
            float lre = s_re[lj], lim = s_im[lj], lkv = s_kv[lj];
            float rre = s_re[rj], rim = s_im[rj], rkv = s_kv[rj];
            s_kv[rj] = rre * lkv + rkv;
            s_re[rj] = rre * lre - rim * lim;
            s_im[rj] = rre * lim + rim * lre;
        }
        __syncthreads();
    }
    for (int n = tid; n < 2048; n += 256) {
        float q = qkv_b[(size_t)n * 3072 + h];
        y[((size_t)b * 2048 + n) * 1024 + h] = q * s_kv[n];
    }
}

// ---------------------------------------------------------------- GEMM (split)
// C[M,N] = (Ah+Al)[M,K] * (Bh+Bl)[N,K]^T, f32 accumulate.
// SPLITB=false: B = Bh only (acc += Ah*Bh + Al*Bh).
// EPI: 0=store f32, 1=+bias store f32, 2=Cf+=, 3=Cf+=+bias,
//      4=gelu(acc+bias)->split bf16, 5=silu(acc)*extra->split bf16
template<int EPI, bool SPLITB>
__global__ __launch_bounds__(256) void gemm_kernel(
    const unsigned short* __restrict__ Ah, const unsigned short* __restrict__ Al,
    const unsigned short* __restrict__ Bh, const unsigned short* __restrict__ Bl,
    const float* __restrict__ bias, const float* __restrict__ extra,
    float* __restrict__ Cf, unsigned short* __restrict__ Cbh,
    unsigned short* __restrict__ Cbl,
    int M, int N, int K)
{
    __shared__ __align__(16) unsigned short AsH[128 * 64];
    __shared__ __align__(16) unsigned short AsL[128 * 64];
    __shared__ __align__(16) unsigned short BsH[128 * 64];
    __shared__ __align__(16) unsigned short BsL[128 * 64];
    const int tid  = threadIdx.x;
    const int lane = tid & 63;
    const int wave = tid >> 6;
    const int bm = blockIdx.x, bn = blockIdx.y;
    const int wm = (wave >> 1) * 64, wn = (wave & 1) * 64;

    fx4 acc[4][4] = {};

    const size_t aRow0 = (size_t)bm * 128;
    const size_t bRow0 = (size_t)bn * 128;

    for (int k0 = 0; k0 < K; k0 += 64) {
        #pragma unroll
        for (int q = 0; q < 4; ++q) {
            const int chunk = q * 256 + tid;
            const int row = chunk >> 3;
            const int cb  = (chunk & 7) * 16;
            const size_t aoff = (aRow0 + row) * K + k0;
            const size_t boff = (bRow0 + row) * K + k0;
            __builtin_amdgcn_global_load_lds((const AS1 void*)((const char*)(Ah + aoff) + cb),
                (AS3 void*)((char*)AsH + chunk * 16), 16, 0, 0);
            __builtin_amdgcn_global_load_lds((const AS1 void*)((const char*)(Al + aoff) + cb),
                (AS3 void*)((char*)AsL + chunk * 16), 16, 0, 0);
            __builtin_amdgcn_global_load_lds((const AS1 void*)((const char*)(Bh + boff) + cb),
                (AS3 void*)((char*)BsH + chunk * 16), 16, 0, 0);
            if (SPLITB)
                __builtin_amdgcn_global_load_lds((const AS1 void*)((const char*)(Bl + boff) + cb),
                    (AS3 void*)((char*)BsL + chunk * 16), 16, 0, 0);
        }
        __syncthreads();

        #pragma unroll
        for (int kk = 0; kk < 2; ++kk) {
            bf16x8 ah[4], al_[4], bh[4], bl[4];
            #pragma unroll
            for (int i = 0; i < 4; ++i) {
                const int row = wm + i * 16 + (lane & 15);
                const int off = row * 128 + kk * 64 + (lane >> 4) * 16;
                ah[i]  = *(const bf16x8*)((const char*)AsH + off);
                al_[i] = *(const bf16x8*)((const char*)AsL + off);
            }
            #pragma unroll
            for (int j = 0; j < 4; ++j) {
                const int row = wn + j * 16 + (lane & 15);
                const int off = row * 128 + kk * 64 + (lane >> 4) * 16;
                bh[j] = *(const bf16x8*)((const char*)BsH + off);
                if (SPLITB) bl[j] = *(const bf16x8*)((const char*)BsL + off);
            }
            #pragma unroll
            for (int i = 0; i < 4; ++i) {
                #pragma unroll
                for (int j = 0; j < 4; ++j) {
                    acc[i][j] = __builtin_amdgcn_mfma_f32_16x16x32_bf16(
                        ah[i], bh[j], acc[i][j], 0, 0, 0);
                    acc[i][j] = __builtin_amdgcn_mfma_f32_16x16x32_bf16(
                        al_[i], bh[j], acc[i][j], 0, 0, 0);
                    if (SPLITB)
                        acc[i][j] = __builtin_amdgcn_mfma_f32_16x16x32_bf16(
                            ah[i], bl[j], acc[i][j], 0, 0, 0);
                }
            }
        }
        __syncthreads();
    }

    const int col_l = lane & 15, row_l = (lane >> 4) * 4;
    #pragma unroll
    for (int i = 0; i < 4; ++i) {
        #pragma unroll
        for (int j = 0; j < 4; ++j) {
            #pragma unroll
            for (int r = 0; r < 4; ++r) {
                const int row = bm * 128 + wm + i * 16 + row_l + r;
                const int col = bn * 128 + wn + j * 16 + col_l;
                const size_t idx = (size_t)row * N + col;
                const float v = acc[i][j][r];
                if (EPI == 0) {
                    Cf[idx] = v;
                } else if (EPI == 1) {
                    Cf[idx] = v + bias[col];
                } else if (EPI == 2) {
                    Cf[idx] += v;
                } else if (EPI == 3) {
                    Cf[idx] += v + bias[col];
                } else if (EPI == 4) {
                    const float t = v + bias[col];
                    const float gelu = 0.5f * t * (1.0f + erff(t * 0.70710678118654752f));
                    split2(gelu, &Cbh[idx], &Cbl[idx]);
                } else if (EPI == 5) {
                    const float s = v / (1.0f + expf(-v));
                    split2(s * extra[idx], &Cbh[idx], &Cbl[idx]);
                }
            }
        }
    }
}

// ---------------------------------------------------------------- host
extern "C" void kernel_launch(void* const* d_in, const int* in_sizes, int n_in,
                              void* d_out, int out_size, void* d_ws, size_t ws_size,
                              hipStream_t stream)
{
    const int*   tokens = (const int*)d_in[0];
    const float* emb  = (const float*)d_in[1];
    const float* g1   = (const float*)d_in[2];
    const float* Wqkv = (const float*)d_in[3];
    const float* Wa   = (const float*)d_in[4];
    const float* ba   = (const float*)d_in[5];
    const float* Wg   = (const float*)d_in[6];
    const float* Wo   = (const float*)d_in[7];
    const float* g2   = (const float*)d_in[8];
    const float* W1   = (const float*)d_in[9];
    const float* b1   = (const float*)d_in[10];
    const float* W2   = (const float*)d_in[11];
    const float* b2   = (const float*)d_in[12];
    const float* gf   = (const float*)d_in[13];
    const float* Wl   = (const float*)d_in[14];
    float* out = (float*)d_out;

    char* ws = (char*)d_ws;
    size_t off = 0;
    auto take = [&](size_t bytes) {
        char* p = ws + off; off += (bytes + 255) & ~(size_t)255; return p;
    };

    // weights: hi + lo, [N][K] bf16
    unsigned short* wqkvH = (unsigned short*)take((size_t)4 * 3072 * 1024 * 2);
    unsigned short* wqkvL = (unsigned short*)take((size_t)4 * 3072 * 1024 * 2);
    unsigned short* waH   = (unsigned short*)take((size_t)4 * 2048 * 1024 * 2);
    unsigned short* waL   = (unsigned short*)take((size_t)4 * 2048 * 1024 * 2);
    unsigned short* wgH   = (unsigned short*)take((size_t)4 * 1024 * 1024 * 2);
    unsigned short* wgL   = (unsigned short*)take((size_t)4 * 1024 * 1024 * 2);
    unsigned short* woH   = (unsigned short*)take((size_t)4 * 1024 * 1024 * 2);
    unsigned short* woL   = (unsigned short*)take((size_t)4 * 1024 * 1024 * 2);
    unsigned short* w1H   = (unsigned short*)take((size_t)4 * 4096 * 1024 * 2);
    unsigned short* w1L   = (unsigned short*)take((size_t)4 * 4096 * 1024 * 2);
    unsigned short* w2H   = (unsigned short*)take((size_t)4 * 1024 * 4096 * 2);
    unsigned short* w2L   = (unsigned short*)take((size_t)4 * 1024 * 4096 * 2);
    unsigned short* wlH   = (unsigned short*)take((size_t)32000 * 1024 * 2);
    // activations
    float*          x     = (float*)take((size_t)4096 * 1024 * 4);
    unsigned short* xnH   = (unsigned short*)take((size_t)4096 * 1024 * 2);
    unsigned short* xnL   = (unsigned short*)take((size_t)4096 * 1024 * 2);
    float*          qkvb  = (float*)take((size_t)4096 * 3072 * 4);
    float*          alb   = (float*)take((size_t)4096 * 2048 * 4);
    float*          yb    = (float*)take((size_t)4096 * 1024 * 4);
    // aliases (lifetimes disjoint, see timeline in comments)
    unsigned short* gatedH = (unsigned short*)alb;                          // 8MB
    unsigned short* gatedL = (unsigned short*)((char*)alb + (size_t)4096*1024*2); // 8MB
    unsigned short* hH     = (unsigned short*)qkvb;                         // 32MB
    unsigned short* hL     = (unsigned short*)alb;                          // 32MB

    const dim3 blk(256);

    transpose_split_kernel<<<dim3(32,  96, 4), blk, 0, stream>>>(Wqkv, wqkvH, wqkvL, 1024, 3072);
    transpose_split_kernel<<<dim3(32,  64, 4), blk, 0, stream>>>(Wa,   waH,   waL,   1024, 2048);
    transpose_split_kernel<<<dim3(32,  32, 4), blk, 0, stream>>>(Wg,   wgH,   wgL,   1024, 1024);
    transpose_split_kernel<<<dim3(32,  32, 4), blk, 0, stream>>>(Wo,   woH,   woL,   1024, 1024);
    transpose_split_kernel<<<dim3(32, 128, 4), blk, 0, stream>>>(W1,   w1H,   w1L,   1024, 4096);
    transpose_split_kernel<<<dim3(128, 32, 4), blk, 0, stream>>>(W2,   w2H,   w2L,   4096, 1024);
    transpose_split_kernel<<<dim3(32, 1000, 1), blk, 0, stream>>>(Wl,  wlH,   nullptr, 1024, 32000);

    embed_kernel<<<4096, blk, 0, stream>>>(tokens, emb, x);

    for (int i = 0; i < 4; ++i) {
        const size_t oq = (size_t)i * 3072 * 1024;
        const size_t oa = (size_t)i * 2048 * 1024;
        const size_t o1 = (size_t)i * 1024 * 1024;
        const size_t of1 = (size_t)i * 4096 * 1024;
        const size_t of2 = (size_t)i * 1024 * 4096;

        rms_split_kernel<<<4096, blk, 0, stream>>>(x, g1 + i * 1024, xnH, xnL);
        gemm_kernel<0, true><<<dim3(32, 24), blk, 0, stream>>>(
            xnH, xnL, wqkvH + oq, wqkvL + oq, nullptr, nullptr,
            qkvb, nullptr, nullptr, 4096, 3072, 1024);
        gemm_kernel<1, true><<<dim3(32, 16), blk, 0, stream>>>(
            xnH, xnL, waH + oa, waL + oa, ba + i * 2048, nullptr,
            alb, nullptr, nullptr, 4096, 2048, 1024);
        scan_kernel<<<2048, blk, 0, stream>>>(qkvb, alb, yb);
        gemm_kernel<5, true><<<dim3(32, 8), blk, 0, stream>>>(
            xnH, xnL, wgH + o1, wgL + o1, nullptr, yb,
            nullptr, gatedH, gatedL, 4096, 1024, 1024);
        gemm_kernel<2, true><<<dim3(32, 8), blk, 0, stream>>>(
            gatedH, gatedL, woH + o1, woL + o1, nullptr, nullptr,
            x, nullptr, nullptr, 4096, 1024, 1024);
        rms_split_kernel<<<4096, blk, 0, stream>>>(x, g2 + i * 1024, xnH, xnL);
        gemm_kernel<4, true><<<dim3(32, 32), blk, 0, stream>>>(
            xnH, xnL, w1H + of1, w1L + of1, b1 + i * 4096, nullptr,
            nullptr, hH, hL, 4096, 4096, 1024);
        gemm_kernel<3, true><<<dim3(32, 8), blk, 0, stream>>>(
            hH, hL, w2H + of2, w2L + of2, b2 + i * 1024, nullptr,
            x, nullptr, nullptr, 4096, 1024, 4096);
    }

    rms_split_kernel<<<4096, blk, 0, stream>>>(x, gf, xnH, xnL);
    gemm_kernel<0, false><<<dim3(32, 250), blk, 0, stream>>>(
        xnH, xnL, wlH, wlH, nullptr, nullptr,
        out, nullptr, nullptr, 4096, 32000, 1024);
}

// Round 5
// 2944.890 us; speedup vs baseline: 1.3284x; 1.3284x over previous
//
#include <hip/hip_runtime.h>

// ---------------------------------------------------------------------------
// Transformer (GateLoop-style) forward, MI355X/gfx950.  Round 5 (= round 4 +
// alias overflow fix: scan scratch region is 64 MiB, Wl-bf16 is only 62.5 MiB
// -> region now allocated as max(64 MiB) so aImT no longer clobbers x).
//  - split-bf16 GEMMs (hi/lo, 3 MFMA) with XOR-swizzled LDS (conflict fix):
//    LDS dest stays linear (global_load_lds requirement), global source slot
//    is pre-swizzled slot^(row&7), ds_read applies the same XOR.  16-way -> 2-way.
//  - scan path: prep kernels transpose to [b*h][n] (coalesced), Brent-Kung
//    scan with padded LDS indexing, y kept transposed and consumed by the
//    gates GEMM epilogue via transposed indexing.
// ---------------------------------------------------------------------------

typedef float fx4 __attribute__((ext_vector_type(4)));
typedef __bf16 bf16x8 __attribute__((ext_vector_type(8)));
typedef unsigned short u16x4 __attribute__((ext_vector_type(4)));

#define AS1 __attribute__((address_space(1)))
#define AS3 __attribute__((address_space(3)))

__device__ __forceinline__ unsigned short f2bf(float f) {
    unsigned u = __float_as_uint(f);
    u += 0x7FFFu + ((u >> 16) & 1u);   // RNE
    return (unsigned short)(u >> 16);
}
__device__ __forceinline__ float bf2f(unsigned short h) {
    return __uint_as_float(((unsigned)h) << 16);
}
__device__ __forceinline__ void split2(float f, unsigned short* hi, unsigned short* lo) {
    unsigned short h = f2bf(f);
    *hi = h;
    *lo = f2bf(f - bf2f(h));
}

// ---------------------------------------------------------------- transpose
// in: f32 [K][N] (batch z) -> hi/lo bf16 [N][K]
__global__ __launch_bounds__(256) void transpose_split_kernel(
    const float* __restrict__ in, unsigned short* __restrict__ hi,
    unsigned short* __restrict__ lo, int K, int N)
{
    __shared__ float tile[32][33];
    const int b = blockIdx.z;
    in += (size_t)b * K * N;
    const size_t obase = (size_t)b * K * N;
    const int k0 = blockIdx.x * 32, n0 = blockIdx.y * 32;
    const int tr = threadIdx.x >> 3;
    const int tc = (threadIdx.x & 7) * 4;
    fx4 v = *(const fx4*)&in[(size_t)(k0 + tr) * N + n0 + tc];
    tile[tr][tc + 0] = v[0]; tile[tr][tc + 1] = v[1];
    tile[tr][tc + 2] = v[2]; tile[tr][tc + 3] = v[3];
    __syncthreads();
    u16x4 oh, ol;
    #pragma unroll
    for (int e = 0; e < 4; ++e) {
        float f = tile[tc + e][tr];
        unsigned short h = f2bf(f);
        oh[e] = h;
        ol[e] = f2bf(f - bf2f(h));
    }
    const size_t oidx = obase + (size_t)(n0 + tr) * K + k0 + tc;
    *(u16x4*)&hi[oidx] = oh;
    if (lo) *(u16x4*)&lo[oidx] = ol;
}

// ---------------------------------------------------------------- embedding
__global__ __launch_bounds__(256) void embed_kernel(
    const int* __restrict__ tokens, const float* __restrict__ emb,
    float* __restrict__ x)
{
    const int row = blockIdx.x;
    const int t = tokens[row];
    const int c = threadIdx.x * 4;
    *(fx4*)&x[(size_t)row * 1024 + c] = *(const fx4*)&emb[(size_t)t * 1024 + c];
}

// ---------------------------------------------------------------- rms -> split bf16
__global__ __launch_bounds__(256) void rms_split_kernel(
    const float* __restrict__ x, const float* __restrict__ g,
    unsigned short* __restrict__ hi, unsigned short* __restrict__ lo)
{
    const int row = blockIdx.x;
    const int c = threadIdx.x * 4;
    fx4 v = *(const fx4*)&x[(size_t)row * 1024 + c];
    float ss = v[0]*v[0] + v[1]*v[1] + v[2]*v[2] + v[3]*v[3];
    #pragma unroll
    for (int off = 32; off > 0; off >>= 1) ss += __shfl_down(ss, off, 64);
    __shared__ float wsum[4];
    if ((threadIdx.x & 63) == 0) wsum[threadIdx.x >> 6] = ss;
    __syncthreads();
    const float nrm = sqrtf(wsum[0] + wsum[1] + wsum[2] + wsum[3]);
    const float scale = 32.0f / fmaxf(nrm, 1e-12f);
    fx4 gg = *(const fx4*)&g[c];
    u16x4 oh, ol;
    #pragma unroll
    for (int e = 0; e < 4; ++e) {
        float f = v[e] * scale * gg[e];
        unsigned short h = f2bf(f);
        oh[e] = h;
        ol[e] = f2bf(f - bf2f(h));
    }
    *(u16x4*)&hi[(size_t)row * 1024 + c] = oh;
    *(u16x4*)&lo[(size_t)row * 1024 + c] = ol;
}

// ---------------------------------------------------------------- scan prep
// qkv [b][n][3072] -> qT[b*1024+h][n], kvT = k*v  (coalesced tiled transpose)
__global__ __launch_bounds__(256) void prep_qkv_kernel(
    const float* __restrict__ qkv, float* __restrict__ qT, float* __restrict__ kvT)
{
    __shared__ float tq[32][33], tkv[32][33];
    const int n0 = blockIdx.x * 32, h0 = blockIdx.y * 32, b = blockIdx.z;
    const int tr = threadIdx.x >> 3;
    const int tc = (threadIdx.x & 7) * 4;
    const float* row = qkv + ((size_t)b * 2048 + n0 + tr) * 3072;
    fx4 qv = *(const fx4*)&row[h0 + tc];
    fx4 kv = *(const fx4*)&row[1024 + h0 + tc];
    fx4 vv = *(const fx4*)&row[2048 + h0 + tc];
    #pragma unroll
    for (int e = 0; e < 4; ++e) { tq[tr][tc + e] = qv[e]; tkv[tr][tc + e] = kv[e] * vv[e]; }
    __syncthreads();
    fx4 oq, okv;
    #pragma unroll
    for (int e = 0; e < 4; ++e) { oq[e] = tq[tc + e][tr]; okv[e] = tkv[tc + e][tr]; }
    const size_t ob = ((size_t)b * 1024 + h0 + tr) * 2048 + n0 + tc;
    *(fx4*)&qT[ob] = oq;
    *(fx4*)&kvT[ob] = okv;
}

// al [b][n][2048] (re,im interleaved per h) -> polar -> aReT/aImT [b*1024+h][n]
__global__ __launch_bounds__(256) void prep_a_kernel(
    const float* __restrict__ al, float* __restrict__ aReT, float* __restrict__ aImT)
{
    __shared__ float tre[32][33], tim[32][33];
    const int n0 = blockIdx.x * 32, h0 = blockIdx.y * 32, b = blockIdx.z;
    const int tr = threadIdx.x >> 3;          // n offset
    const int tcf = (threadIdx.x & 7) * 8;    // float offset (covers 4 heads)
    const float* row = al + ((size_t)b * 2048 + n0 + tr) * 2048 + 2 * h0;
    fx4 v0 = *(const fx4*)&row[tcf];
    fx4 v1 = *(const fx4*)&row[tcf + 4];
    #pragma unroll
    for (int p = 0; p < 4; ++p) {
        float re = (p < 2) ? v0[2 * p] : v1[2 * (p - 2)];
        float im = (p < 2) ? v0[2 * p + 1] : v1[2 * (p - 2) + 1];
        float r = sqrtf(re * re + im * im);
        float sg = 1.0f / (1.0f + expf(-r));
        float a_re, a_im;
        if (r > 0.0f) { float inv = sg / r; a_re = re * inv; a_im = im * inv; }
        else          { a_re = sg; a_im = 0.0f; }
        tre[tr][tcf / 2 + p] = a_re;
        tim[tr][tcf / 2 + p] = a_im;
    }
    __syncthreads();
    const int tc = (threadIdx.x & 7) * 4;
    fx4 ore, oim;
    #pragma unroll
    for (int e = 0; e < 4; ++e) { ore[e] = tre[tc + e][tr]; oim[e] = tim[tc + e][tr]; }
    const size_t ob = ((size_t)b * 1024 + h0 + tr) * 2048 + n0 + tc;
    *(fx4*)&aReT[ob] = ore;
    *(fx4*)&aImT[ob] = oim;
}

// ---------------------------------------------------------------- gate-loop scan
// One block per (b,h), inputs/outputs transposed (fully coalesced).
// Brent-Kung == jax.lax.associative_scan bracketing (binop NON-associative).
__device__ __forceinline__ int pidx(int i) { return i + (i >> 5); }

__global__ __launch_bounds__(256) void scanT_kernel(
    const float* __restrict__ kvT, const float* __restrict__ aReT,
    const float* __restrict__ aImT, const float* __restrict__ qT,
    float* __restrict__ yT)
{
    const int tid = threadIdx.x;
    const size_t base = (size_t)blockIdx.x * 2048;
    __shared__ float s_re[2048 + 64], s_im[2048 + 64], s_kv[2048 + 64];

    for (int i = tid; i < 512; i += 256) {
        fx4 kv = *(const fx4*)&kvT[base + i * 4];
        fx4 re = *(const fx4*)&aReT[base + i * 4];
        fx4 im = *(const fx4*)&aImT[base + i * 4];
        #pragma unroll
        for (int e = 0; e < 4; ++e) {
            const int j = pidx(i * 4 + e);
            s_kv[j] = kv[e]; s_re[j] = re[e]; s_im[j] = im[e];
        }
    }
    __syncthreads();

    for (int d = 0; d < 11; ++d) {
        const int half = 1 << d, stride = half << 1;
        const int npairs = 2048 >> (d + 1);
        for (int i = tid; i < npairs; i += 256) {
            const int rj = pidx(i * stride + stride - 1);
            const int lj = pidx(i * stride + stride - 1 - half);
            float lre = s_re[lj], lim = s_im[lj], lkv = s_kv[lj];
            float rre = s_re[rj], rim = s_im[rj], rkv = s_kv[rj];
            s_kv[rj] = rre * lkv + rkv;
            s_re[rj] = rre * lre - rim * lim;
            s_im[rj] = rre * lim + rim * lre;
        }
        __syncthreads();
    }
    for (int d = 9; d >= 0; --d) {
        const int w = 1 << d;
        const int nupd = (2048 >> (d + 1)) - 1;
        for (int t = tid; t < nupd; t += 256) {
            const int i = t + 1;
            const int rj = pidx((2 * i + 1) * w - 1);
            const int lj = pidx(2 * i * w - 1);
            float lre = s_re[lj], lim = s_im[lj], lkv = s_kv[lj];
            float rre = s_re[rj], rim = s_im[rj], rkv = s_kv[rj];
            s_kv[rj] = rre * lkv + rkv;
            s_re[rj] = rre * lre - rim * lim;
            s_im[rj] = rre * lim + rim * lre;
        }
        __syncthreads();
    }
    for (int i = tid; i < 512; i += 256) {
        fx4 q = *(const fx4*)&qT[base + i * 4];
        fx4 o;
        #pragma unroll
        for (int e = 0; e < 4; ++e) o[e] = q[e] * s_kv[pidx(i * 4 + e)];
        *(fx4*)&yT[base + i * 4] = o;
    }
}

// ---------------------------------------------------------------- GEMM (split, swizzled)
// C[M,N] = (Ah+Al)[M,K] * (Bh+Bl)[N,K]^T, f32 acc.  LDS XOR swizzle:
// LDS[row][slot] holds global slot^(row&7) (16B granules); reads XOR the same.
// EPI: 0=store f32, 1=+bias f32, 2=Cf+=, 3=Cf+=+bias,
//      4=gelu(acc+bias)->split bf16, 5=silu(acc)*extra->split bf16
// ET: extra is transposed [b*1024+col][n] (scan output layout)
template<int EPI, bool SPLITB, bool ET>
__global__ __launch_bounds__(256) void gemm_kernel(
    const unsigned short* __restrict__ Ah, const unsigned short* __restrict__ Al,
    const unsigned short* __restrict__ Bh, const unsigned short* __restrict__ Bl,
    const float* __restrict__ bias, const float* __restrict__ extra,
    float* __restrict__ Cf, unsigned short* __restrict__ Cbh,
    unsigned short* __restrict__ Cbl,
    int M, int N, int K)
{
    __shared__ __align__(16) unsigned short AsH[128 * 64];
    __shared__ __align__(16) unsigned short AsL[128 * 64];
    __shared__ __align__(16) unsigned short BsH[128 * 64];
    __shared__ __align__(16) unsigned short BsL[128 * 64];
    const int tid  = threadIdx.x;
    const int lane = tid & 63;
    const int wave = tid >> 6;
    const int bm = blockIdx.x, bn = blockIdx.y;
    const int wm = (wave >> 1) * 64, wn = (wave & 1) * 64;

    fx4 acc[4][4] = {};

    const size_t aRow0 = (size_t)bm * 128;
    const size_t bRow0 = (size_t)bn * 128;

    for (int k0 = 0; k0 < K; k0 += 64) {
        #pragma unroll
        for (int q = 0; q < 4; ++q) {
            const int chunk = q * 256 + tid;
            const int row = chunk >> 3;
            const int slot = chunk & 7;
            const int gs = slot ^ (row & 7);          // pre-swizzled source slot
            const size_t aoff = (aRow0 + row) * K + k0 + gs * 8;
            const size_t boff = (bRow0 + row) * K + k0 + gs * 8;
            __builtin_amdgcn_global_load_lds((const AS1 void*)(Ah + aoff),
                (AS3 void*)((char*)AsH + chunk * 16), 16, 0, 0);
            __builtin_amdgcn_global_load_lds((const AS1 void*)(Al + aoff),
                (AS3 void*)((char*)AsL + chunk * 16), 16, 0, 0);
            __builtin_amdgcn_global_load_lds((const AS1 void*)(Bh + boff),
                (AS3 void*)((char*)BsH + chunk * 16), 16, 0, 0);
            if (SPLITB)
                __builtin_amdgcn_global_load_lds((const AS1 void*)(Bl + boff),
                    (AS3 void*)((char*)BsL + chunk * 16), 16, 0, 0);
        }
        __syncthreads();

        #pragma unroll
        for (int kk = 0; kk < 2; ++kk) {
            const int sw = ((kk * 4 + (lane >> 4)) ^ (lane & 7)) * 16;  // row&7 == lane&7
            bf16x8 ah[4], al_[4], bh[4], bl[4];
            #pragma unroll
            for (int i = 0; i < 4; ++i) {
                const int row = wm + i * 16 + (lane & 15);
                const int off = row * 128 + sw;
                ah[i]  = *(const bf16x8*)((const char*)AsH + off);
                al_[i] = *(const bf16x8*)((const char*)AsL + off);
            }
            #pragma unroll
            for (int j = 0; j < 4; ++j) {
                const int row = wn + j * 16 + (lane & 15);
                const int off = row * 128 + sw;
                bh[j] = *(const bf16x8*)((const char*)BsH + off);
                if (SPLITB) bl[j] = *(const bf16x8*)((const char*)BsL + off);
            }
            #pragma unroll
            for (int i = 0; i < 4; ++i) {
                #pragma unroll
                for (int j = 0; j < 4; ++j) {
                    acc[i][j] = __builtin_amdgcn_mfma_f32_16x16x32_bf16(
                        ah[i], bh[j], acc[i][j], 0, 0, 0);
                    acc[i][j] = __builtin_amdgcn_mfma_f32_16x16x32_bf16(
                        al_[i], bh[j], acc[i][j], 0, 0, 0);
                    if (SPLITB)
                        acc[i][j] = __builtin_amdgcn_mfma_f32_16x16x32_bf16(
                            ah[i], bl[j], acc[i][j], 0, 0, 0);
                }
            }
        }
        __syncthreads();
    }

    const int col_l = lane & 15, row_l = (lane >> 4) * 4;
    #pragma unroll
    for (int i = 0; i < 4; ++i) {
        #pragma unroll
        for (int j = 0; j < 4; ++j) {
            #pragma unroll
            for (int r = 0; r < 4; ++r) {
                const int row = bm * 128 + wm + i * 16 + row_l + r;
                const int col = bn * 128 + wn + j * 16 + col_l;
                const size_t idx = (size_t)row * N + col;
                const float v = acc[i][j][r];
                if (EPI == 0) {
                    Cf[idx] = v;
                } else if (EPI == 1) {
                    Cf[idx] = v + bias[col];
                } else if (EPI == 2) {
                    Cf[idx] += v;
                } else if (EPI == 3) {
                    Cf[idx] += v + bias[col];
                } else if (EPI == 4) {
                    const float t = v + bias[col];
                    const float gelu = 0.5f * t * (1.0f + erff(t * 0.70710678118654752f));
                    split2(gelu, &Cbh[idx], &Cbl[idx]);
                } else if (EPI == 5) {
                    const size_t eidx = ET
                        ? ((size_t)(row >> 11) * 1024 + col) * 2048 + (row & 2047)
                        : idx;
                    const float s = v / (1.0f + expf(-v));
                    split2(s * extra[eidx], &Cbh[idx], &Cbl[idx]);
                }
            }
        }
    }
}

// ---------------------------------------------------------------- host
extern "C" void kernel_launch(void* const* d_in, const int* in_sizes, int n_in,
                              void* d_out, int out_size, void* d_ws, size_t ws_size,
                              hipStream_t stream)
{
    const int*   tokens = (const int*)d_in[0];
    const float* emb  = (const float*)d_in[1];
    const float* g1   = (const float*)d_in[2];
    const float* Wqkv = (const float*)d_in[3];
    const float* Wa   = (const float*)d_in[4];
    const float* ba   = (const float*)d_in[5];
    const float* Wg   = (const float*)d_in[6];
    const float* Wo   = (const float*)d_in[7];
    const float* g2   = (const float*)d_in[8];
    const float* W1   = (const float*)d_in[9];
    const float* b1   = (const float*)d_in[10];
    const float* W2   = (const float*)d_in[11];
    const float* b2   = (const float*)d_in[12];
    const float* gf   = (const float*)d_in[13];
    const float* Wl   = (const float*)d_in[14];
    float* out = (float*)d_out;

    char* ws = (char*)d_ws;
    size_t off = 0;
    auto take = [&](size_t bytes) {
        char* p = ws + off; off += (bytes + 255) & ~(size_t)255; return p;
    };

    unsigned short* wqkvH = (unsigned short*)take((size_t)4 * 3072 * 1024 * 2);
    unsigned short* wqkvL = (unsigned short*)take((size_t)4 * 3072 * 1024 * 2);
    unsigned short* waH   = (unsigned short*)take((size_t)4 * 2048 * 1024 * 2);
    unsigned short* waL   = (unsigned short*)take((size_t)4 * 2048 * 1024 * 2);
    unsigned short* wgH   = (unsigned short*)take((size_t)4 * 1024 * 1024 * 2);
    unsigned short* wgL   = (unsigned short*)take((size_t)4 * 1024 * 1024 * 2);
    unsigned short* woH   = (unsigned short*)take((size_t)4 * 1024 * 1024 * 2);
    unsigned short* woL   = (unsigned short*)take((size_t)4 * 1024 * 1024 * 2);
    unsigned short* w1H   = (unsigned short*)take((size_t)4 * 4096 * 1024 * 2);
    unsigned short* w1L   = (unsigned short*)take((size_t)4 * 4096 * 1024 * 2);
    unsigned short* w2H   = (unsigned short*)take((size_t)4 * 1024 * 4096 * 2);
    unsigned short* w2L   = (unsigned short*)take((size_t)4 * 1024 * 4096 * 2);
    // Region hosting BOTH the 4x16MiB scan scratch (during layers) and the
    // transposed Wl bf16 (62.5 MiB, written after the layers). Sized for the
    // larger of the two: 64 MiB.  (Round-4 bug: sized 62.5 MiB -> aImT's last
    // 1.5 MiB clobbered x.)
    char*           wlRegion = take((size_t)64 << 20);
    unsigned short* wlH   = (unsigned short*)wlRegion;
    float*          x     = (float*)take((size_t)4096 * 1024 * 4);
    unsigned short* xnH   = (unsigned short*)take((size_t)4096 * 1024 * 2);
    unsigned short* xnL   = (unsigned short*)take((size_t)4096 * 1024 * 2);
    float*          qkvb  = (float*)take((size_t)4096 * 3072 * 4);   // 48MiB
    float*          alb   = (float*)take((size_t)4096 * 2048 * 4);   // 32MiB

    // scan transposed arrays live in wlRegion (Wl transposed only at the end)
    float* qT   = (float*)wlRegion;                              // 16MiB
    float* kvT  = (float*)(wlRegion + ((size_t)16 << 20));       // 16MiB
    float* aReT = (float*)(wlRegion + ((size_t)32 << 20));       // 16MiB
    float* aImT = (float*)(wlRegion + ((size_t)48 << 20));       // 16MiB
    // gated / y / ffn-hidden alias alb & qkvb (lifetimes disjoint)
    unsigned short* gatedH = (unsigned short*)alb;                                  // 8MiB
    unsigned short* gatedL = (unsigned short*)((char*)alb + ((size_t)4096*1024*2)); // 8MiB
    float*          yT     = (float*)((char*)alb + ((size_t)16 << 20));             // 16MiB
    unsigned short* hH     = (unsigned short*)qkvb;   // 32MiB
    unsigned short* hL     = (unsigned short*)alb;    // 32MiB

    const dim3 blk(256);

    transpose_split_kernel<<<dim3(32,  96, 4), blk, 0, stream>>>(Wqkv, wqkvH, wqkvL, 1024, 3072);
    transpose_split_kernel<<<dim3(32,  64, 4), blk, 0, stream>>>(Wa,   waH,   waL,   1024, 2048);
    transpose_split_kernel<<<dim3(32,  32, 4), blk, 0, stream>>>(Wg,   wgH,   wgL,   1024, 1024);
    transpose_split_kernel<<<dim3(32,  32, 4), blk, 0, stream>>>(Wo,   woH,   woL,   1024, 1024);
    transpose_split_kernel<<<dim3(32, 128, 4), blk, 0, stream>>>(W1,   w1H,   w1L,   1024, 4096);
    transpose_split_kernel<<<dim3(128, 32, 4), blk, 0, stream>>>(W2,   w2H,   w2L,   4096, 1024);

    embed_kernel<<<4096, blk, 0, stream>>>(tokens, emb, x);

    for (int i = 0; i < 4; ++i) {
        const size_t oq = (size_t)i * 3072 * 1024;
        const size_t oa = (size_t)i * 2048 * 1024;
        const size_t o1 = (size_t)i * 1024 * 1024;
        const size_t of1 = (size_t)i * 4096 * 1024;
        const size_t of2 = (size_t)i * 1024 * 4096;

        rms_split_kernel<<<4096, blk, 0, stream>>>(x, g1 + i * 1024, xnH, xnL);
        gemm_kernel<0, true, false><<<dim3(32, 24), blk, 0, stream>>>(
            xnH, xnL, wqkvH + oq, wqkvL + oq, nullptr, nullptr,
            qkvb, nullptr, nullptr, 4096, 3072, 1024);
        gemm_kernel<1, true, false><<<dim3(32, 16), blk, 0, stream>>>(
            xnH, xnL, waH + oa, waL + oa, ba + i * 2048, nullptr,
            alb, nullptr, nullptr, 4096, 2048, 1024);
        prep_qkv_kernel<<<dim3(64, 32, 2), blk, 0, stream>>>(qkvb, qT, kvT);
        prep_a_kernel<<<dim3(64, 32, 2), blk, 0, stream>>>(alb, aReT, aImT);
        scanT_kernel<<<2048, blk, 0, stream>>>(kvT, aReT, aImT, qT, yT);
        gemm_kernel<5, true, true><<<dim3(32, 8), blk, 0, stream>>>(
            xnH, xnL, wgH + o1, wgL + o1, nullptr, yT,
            nullptr, gatedH, gatedL, 4096, 1024, 1024);
        gemm_kernel<2, true, false><<<dim3(32, 8), blk, 0, stream>>>(
            gatedH, gatedL, woH + o1, woL + o1, nullptr, nullptr,
            x, nullptr, nullptr, 4096, 1024, 1024);
        rms_split_kernel<<<4096, blk, 0, stream>>>(x, g2 + i * 1024, xnH, xnL);
        gemm_kernel<4, true, false><<<dim3(32, 32), blk, 0, stream>>>(
            xnH, xnL, w1H + of1, w1L + of1, b1 + i * 4096, nullptr,
            nullptr, hH, hL, 4096, 4096, 1024);
        gemm_kernel<3, true, false><<<dim3(32, 8), blk, 0, stream>>>(
            hH, hL, w2H + of2, w2L + of2, b2 + i * 1024, nullptr,
            x, nullptr, nullptr, 4096, 1024, 4096);
    }

    // Wl transpose deferred: its region was scan scratch during the layers
    transpose_split_kernel<<<dim3(32, 1000, 1), blk, 0, stream>>>(Wl, wlH, nullptr, 1024, 32000);

    rms_split_kernel<<<4096, blk, 0, stream>>>(x, gf, xnH, xnL);
    gemm_kernel<0, false, false><<<dim3(32, 250), blk, 0, stream>>>(
        xnH, xnL, wlH, wlH, nullptr, nullptr,
        out, nullptr, nullptr, 4096, 32000, 1024);
}

// Round 6
// 2105.148 us; speedup vs baseline: 1.8582x; 1.3989x over previous
//
#include <hip/hip_runtime.h>

// ---------------------------------------------------------------------------
// Transformer (GateLoop-style) forward, MI355X/gfx950.  Round 6.
//  - ALL GEMMs single-pass fp16 (mfma_f32_16x16x32_f16, f32 accumulate).
//    Error analysis: fp16 rounding = bf16/8; round-1 all-bf16 gave 0.317
//    absmax -> predict ~0.04 < 0.075 threshold.
//  - qkv|Wa|Wg fused into one N=6144 GEMM (grid 1536), epilogue routes by
//    column tile; gating (silu(G)*y) moved to a coalesced tiled kernel.
//  - XOR-swizzled LDS staging kept (verified: bank conflicts 1.5e8 -> 0).
//  - scan path unchanged (f32, transposed coalesced, Brent-Kung == JAX
//    associative_scan bracketing).
// ---------------------------------------------------------------------------

typedef float fx4 __attribute__((ext_vector_type(4)));
typedef _Float16 f16x8 __attribute__((ext_vector_type(8)));
typedef _Float16 f16x4 __attribute__((ext_vector_type(4)));

#define AS1 __attribute__((address_space(1)))
#define AS3 __attribute__((address_space(3)))

// ---------------------------------------------------------------- transpose
// in: f32 [K][N] (batch z) -> fp16 [N][K] at out + z*ostride
__global__ __launch_bounds__(256) void transpose_f16_kernel(
    const float* __restrict__ in, _Float16* __restrict__ out,
    int K, int N, size_t ostride)
{
    __shared__ float tile[32][33];
    const int b = blockIdx.z;
    in  += (size_t)b * K * N;
    out += (size_t)b * ostride;
    const int k0 = blockIdx.x * 32, n0 = blockIdx.y * 32;
    const int tr = threadIdx.x >> 3;
    const int tc = (threadIdx.x & 7) * 4;
    fx4 v = *(const fx4*)&in[(size_t)(k0 + tr) * N + n0 + tc];
    tile[tr][tc + 0] = v[0]; tile[tr][tc + 1] = v[1];
    tile[tr][tc + 2] = v[2]; tile[tr][tc + 3] = v[3];
    __syncthreads();
    f16x4 o;
    #pragma unroll
    for (int e = 0; e < 4; ++e) o[e] = (_Float16)tile[tc + e][tr];
    *(f16x4*)&out[(size_t)(n0 + tr) * K + k0 + tc] = o;
}

// ---------------------------------------------------------------- embedding
__global__ __launch_bounds__(256) void embed_kernel(
    const int* __restrict__ tokens, const float* __restrict__ emb,
    float* __restrict__ x)
{
    const int row = blockIdx.x;
    const int t = tokens[row];
    const int c = threadIdx.x * 4;
    *(fx4*)&x[(size_t)row * 1024 + c] = *(const fx4*)&emb[(size_t)t * 1024 + c];
}

// ---------------------------------------------------------------- rms -> fp16
__global__ __launch_bounds__(256) void rms_f16_kernel(
    const float* __restrict__ x, const float* __restrict__ g,
    _Float16* __restrict__ outh)
{
    const int row = blockIdx.x;
    const int c = threadIdx.x * 4;
    fx4 v = *(const fx4*)&x[(size_t)row * 1024 + c];
    float ss = v[0]*v[0] + v[1]*v[1] + v[2]*v[2] + v[3]*v[3];
    #pragma unroll
    for (int off = 32; off > 0; off >>= 1) ss += __shfl_down(ss, off, 64);
    __shared__ float wsum[4];
    if ((threadIdx.x & 63) == 0) wsum[threadIdx.x >> 6] = ss;
    __syncthreads();
    const float nrm = sqrtf(wsum[0] + wsum[1] + wsum[2] + wsum[3]);
    const float scale = 32.0f / fmaxf(nrm, 1e-12f);
    fx4 gg = *(const fx4*)&g[c];
    f16x4 o;
    #pragma unroll
    for (int e = 0; e < 4; ++e) o[e] = (_Float16)(v[e] * scale * gg[e]);
    *(f16x4*)&outh[(size_t)row * 1024 + c] = o;
}

// ---------------------------------------------------------------- scan prep
// qkv [b][n][3072] -> qT[b*1024+h][n], kvT = k*v  (coalesced tiled transpose)
__global__ __launch_bounds__(256) void prep_qkv_kernel(
    const float* __restrict__ qkv, float* __restrict__ qT, float* __restrict__ kvT)
{
    __shared__ float tq[32][33], tkv[32][33];
    const int n0 = blockIdx.x * 32, h0 = blockIdx.y * 32, b = blockIdx.z;
    const int tr = threadIdx.x >> 3;
    const int tc = (threadIdx.x & 7) * 4;
    const float* row = qkv + ((size_t)b * 2048 + n0 + tr) * 3072;
    fx4 qv = *(const fx4*)&row[h0 + tc];
    fx4 kv = *(const fx4*)&row[1024 + h0 + tc];
    fx4 vv = *(const fx4*)&row[2048 + h0 + tc];
    #pragma unroll
    for (int e = 0; e < 4; ++e) { tq[tr][tc + e] = qv[e]; tkv[tr][tc + e] = kv[e] * vv[e]; }
    __syncthreads();
    fx4 oq, okv;
    #pragma unroll
    for (int e = 0; e < 4; ++e) { oq[e] = tq[tc + e][tr]; okv[e] = tkv[tc + e][tr]; }
    const size_t ob = ((size_t)b * 1024 + h0 + tr) * 2048 + n0 + tc;
    *(fx4*)&qT[ob] = oq;
    *(fx4*)&kvT[ob] = okv;
}

// al [b][n][2048] (re,im interleaved per h) -> polar -> aReT/aImT [b*1024+h][n]
__global__ __launch_bounds__(256) void prep_a_kernel(
    const float* __restrict__ al, float* __restrict__ aReT, float* __restrict__ aImT)
{
    __shared__ float tre[32][33], tim[32][33];
    const int n0 = blockIdx.x * 32, h0 = blockIdx.y * 32, b = blockIdx.z;
    const int tr = threadIdx.x >> 3;          // n offset
    const int tcf = (threadIdx.x & 7) * 8;    // float offset (covers 4 heads)
    const float* row = al + ((size_t)b * 2048 + n0 + tr) * 2048 + 2 * h0;
    fx4 v0 = *(const fx4*)&row[tcf];
    fx4 v1 = *(const fx4*)&row[tcf + 4];
    #pragma unroll
    for (int p = 0; p < 4; ++p) {
        float re = (p < 2) ? v0[2 * p] : v1[2 * (p - 2)];
        float im = (p < 2) ? v0[2 * p + 1] : v1[2 * (p - 2) + 1];
        float r = sqrtf(re * re + im * im);
        float sg = 1.0f / (1.0f + expf(-r));
        float a_re, a_im;
        if (r > 0.0f) { float inv = sg / r; a_re = re * inv; a_im = im * inv; }
        else          { a_re = sg; a_im = 0.0f; }
        tre[tr][tcf / 2 + p] = a_re;
        tim[tr][tcf / 2 + p] = a_im;
    }
    __syncthreads();
    const int tc = (threadIdx.x & 7) * 4;
    fx4 ore, oim;
    #pragma unroll
    for (int e = 0; e < 4; ++e) { ore[e] = tre[tc + e][tr]; oim[e] = tim[tc + e][tr]; }
    const size_t ob = ((size_t)b * 1024 + h0 + tr) * 2048 + n0 + tc;
    *(fx4*)&aReT[ob] = ore;
    *(fx4*)&aImT[ob] = oim;
}

// ---------------------------------------------------------------- gate-loop scan
// One block per (b,h), inputs/outputs transposed (fully coalesced).
// Brent-Kung == jax.lax.associative_scan bracketing (binop NON-associative).
__device__ __forceinline__ int pidx(int i) { return i + (i >> 5); }

__global__ __launch_bounds__(256) void scanT_kernel(
    const float* __restrict__ kvT, const float* __restrict__ aReT,
    const float* __restrict__ aImT, const float* __restrict__ qT,
    float* __restrict__ yT)
{
    const int tid = threadIdx.x;
    const size_t base = (size_t)blockIdx.x * 2048;
    __shared__ float s_re[2048 + 64], s_im[2048 + 64], s_kv[2048 + 64];

    for (int i = tid; i < 512; i += 256) {
        fx4 kv = *(const fx4*)&kvT[base + i * 4];
        fx4 re = *(const fx4*)&aReT[base + i * 4];
        fx4 im = *(const fx4*)&aImT[base + i * 4];
        #pragma unroll
        for (int e = 0; e < 4; ++e) {
            const int j = pidx(i * 4 + e);
            s_kv[j] = kv[e]; s_re[j] = re[e]; s_im[j] = im[e];
        }
    }
    __syncthreads();

    for (int d = 0; d < 11; ++d) {
        const int half = 1 << d, stride = half << 1;
        const int npairs = 2048 >> (d + 1);
        for (int i = tid; i < npairs; i += 256) {
            const int rj = pidx(i * stride + stride - 1);
            const int lj = pidx(i * stride + stride - 1 - half);
            float lre = s_re[lj], lim = s_im[lj], lkv = s_kv[lj];
            float rre = s_re[rj], rim = s_im[rj], rkv = s_kv[rj];
            s_kv[rj] = rre * lkv + rkv;
            s_re[rj] = rre * lre - rim * lim;
            s_im[rj] = rre * lim + rim * lre;
        }
        __syncthreads();
    }
    for (int d = 9; d >= 0; --d) {
        const int w = 1 << d;
        const int nupd = (2048 >> (d + 1)) - 1;
        for (int t = tid; t < nupd; t += 256) {
            const int i = t + 1;
            const int rj = pidx((2 * i + 1) * w - 1);
            const int lj = pidx(2 * i * w - 1);
            float lre = s_re[lj], lim = s_im[lj], lkv = s_kv[lj];
            float rre = s_re[rj], rim = s_im[rj], rkv = s_kv[rj];
            s_kv[rj] = rre * lkv + rkv;
            s_re[rj] = rre * lre - rim * lim;
            s_im[rj] = rre * lim + rim * lre;
        }
        __syncthreads();
    }
    for (int i = tid; i < 512; i += 256) {
        fx4 q = *(const fx4*)&qT[base + i * 4];
        fx4 o;
        #pragma unroll
        for (int e = 0; e < 4; ++e) o[e] = q[e] * s_kv[pidx(i * 4 + e)];
        *(fx4*)&yT[base + i * 4] = o;
    }
}

// ---------------------------------------------------------------- gating
// gated[n][h] = fp16( silu(G[n][h]) * y[h][n] )   (y transposed via LDS tile)
__global__ __launch_bounds__(256) void gate_kernel(
    const float* __restrict__ G, const float* __restrict__ yT,
    _Float16* __restrict__ gated)
{
    __shared__ float ty[32][33];
    const int n0 = blockIdx.x * 32, h0 = blockIdx.y * 32, b = blockIdx.z;
    const int tr = threadIdx.x >> 3;
    const int tc = (threadIdx.x & 7) * 4;
    // load yT[b*1024+h0+tr][n0+tc..] coalesced
    fx4 yv = *(const fx4*)&yT[((size_t)b * 1024 + h0 + tr) * 2048 + n0 + tc];
    #pragma unroll
    for (int e = 0; e < 4; ++e) ty[tr][tc + e] = yv[e];
    __syncthreads();
    const size_t grow = ((size_t)b * 2048 + n0 + tr) * 1024 + h0 + tc;
    fx4 gv = *(const fx4*)&G[grow];
    f16x4 o;
    #pragma unroll
    for (int e = 0; e < 4; ++e) {
        const float s = gv[e] / (1.0f + expf(-gv[e]));   // silu
        o[e] = (_Float16)(s * ty[tc + e][tr]);
    }
    *(f16x4*)&gated[grow] = o;
}

// ---------------------------------------------------------------- GEMM (fp16, swizzled)
// C[M,N] = A[M,K](fp16) * Bt[N,K]^T(fp16), f32 accumulate.
// LDS XOR swizzle: LDS[row][slot] holds global slot^(row&7) (16B granules);
// ds_read applies the same XOR (involution; verified round 5: conflicts -> 0).
// EPI: 0=store f32, 2=Cf+=v, 3=Cf+=v+bias, 4=Ch=f16(gelu(v+bias)),
//      6=fused routing: bn<24 -> Cf(qkv, ld 3072); bn<40 -> Cf2+bias(al, ld
//        2048, bias idx col-3072); else Cf3(G, ld 1024)
template<int EPI>
__global__ __launch_bounds__(256) void gemm_kernel(
    const _Float16* __restrict__ A, const _Float16* __restrict__ Bt,
    const float* __restrict__ bias,
    float* __restrict__ Cf, float* __restrict__ Cf2, float* __restrict__ Cf3,
    _Float16* __restrict__ Ch,
    int M, int N, int K)
{
    __shared__ __align__(16) _Float16 As[128 * 64];
    __shared__ __align__(16) _Float16 Bs[128 * 64];
    const int tid  = threadIdx.x;
    const int lane = tid & 63;
    const int wave = tid >> 6;
    const int bm = blockIdx.x, bn = blockIdx.y;
    const int wm = (wave >> 1) * 64, wn = (wave & 1) * 64;

    fx4 acc[4][4] = {};

    const size_t aRow0 = (size_t)bm * 128;
    const size_t bRow0 = (size_t)bn * 128;

    for (int k0 = 0; k0 < K; k0 += 64) {
        #pragma unroll
        for (int q = 0; q < 4; ++q) {
            const int chunk = q * 256 + tid;          // 0..1023
            const int row = chunk >> 3;               // 0..127
            const int slot = chunk & 7;
            const int gs = slot ^ (row & 7);          // pre-swizzled source slot
            const size_t aoff = (aRow0 + row) * K + k0 + gs * 8;
            const size_t boff = (bRow0 + row) * K + k0 + gs * 8;
            __builtin_amdgcn_global_load_lds((const AS1 void*)(A + aoff),
                (AS3 void*)((char*)As + chunk * 16), 16, 0, 0);
            __builtin_amdgcn_global_load_lds((const AS1 void*)(Bt + boff),
                (AS3 void*)((char*)Bs + chunk * 16), 16, 0, 0);
        }
        __syncthreads();

        #pragma unroll
        for (int kk = 0; kk < 2; ++kk) {
            const int sw = ((kk * 4 + (lane >> 4)) ^ (lane & 7)) * 16;
            f16x8 af[4], bf[4];
            #pragma unroll
            for (int i = 0; i < 4; ++i) {
                const int row = wm + i * 16 + (lane & 15);
                af[i] = *(const f16x8*)((const char*)As + row * 128 + sw);
            }
            #pragma unroll
            for (int j = 0; j < 4; ++j) {
                const int row = wn + j * 16 + (lane & 15);
                bf[j] = *(const f16x8*)((const char*)Bs + row * 128 + sw);
            }
            #pragma unroll
            for (int i = 0; i < 4; ++i)
                #pragma unroll
                for (int j = 0; j < 4; ++j)
                    acc[i][j] = __builtin_amdgcn_mfma_f32_16x16x32_f16(
                        af[i], bf[j], acc[i][j], 0, 0, 0);
        }
        __syncthreads();
    }

    // epilogue: C/D layout col=lane&15, row=(lane>>4)*4+r
    const int col_l = lane & 15, row_l = (lane >> 4) * 4;
    #pragma unroll
    for (int i = 0; i < 4; ++i) {
        #pragma unroll
        for (int j = 0; j < 4; ++j) {
            #pragma unroll
            for (int r = 0; r < 4; ++r) {
                const int row = bm * 128 + wm + i * 16 + row_l + r;
                const int col = bn * 128 + wn + j * 16 + col_l;
                const float v = acc[i][j][r];
                if (EPI == 0) {
                    Cf[(size_t)row * N + col] = v;
                } else if (EPI == 2) {
                    Cf[(size_t)row * N + col] += v;
                } else if (EPI == 3) {
                    Cf[(size_t)row * N + col] += v + bias[col];
                } else if (EPI == 4) {
                    const float t = v + bias[col];
                    const float gelu = 0.5f * t * (1.0f + erff(t * 0.70710678118654752f));
                    Ch[(size_t)row * N + col] = (_Float16)gelu;
                } else if (EPI == 6) {
                    if (bn < 24)      Cf [(size_t)row * 3072 + col] = v;
                    else if (bn < 40) Cf2[(size_t)row * 2048 + (col - 3072)] = v + bias[col - 3072];
                    else              Cf3[(size_t)row * 1024 + (col - 5120)] = v;
                }
            }
        }
    }
}

// ---------------------------------------------------------------- host
extern "C" void kernel_launch(void* const* d_in, const int* in_sizes, int n_in,
                              void* d_out, int out_size, void* d_ws, size_t ws_size,
                              hipStream_t stream)
{
    const int*   tokens = (const int*)d_in[0];
    const float* emb  = (const float*)d_in[1];
    const float* g1   = (const float*)d_in[2];
    const float* Wqkv = (const float*)d_in[3];
    const float* Wa   = (const float*)d_in[4];
    const float* ba   = (const float*)d_in[5];
    const float* Wg   = (const float*)d_in[6];
    const float* Wo   = (const float*)d_in[7];
    const float* g2   = (const float*)d_in[8];
    const float* W1   = (const float*)d_in[9];
    const float* b1   = (const float*)d_in[10];
    const float* W2   = (const float*)d_in[11];
    const float* b2   = (const float*)d_in[12];
    const float* gf   = (const float*)d_in[13];
    const float* Wl   = (const float*)d_in[14];
    float* out = (float*)d_out;

    char* ws = (char*)d_ws;
    size_t off = 0;
    auto take = [&](size_t bytes) {
        char* p = ws + off; off += (bytes + 255) & ~(size_t)255; return p;
    };

    // fp16 weights
    _Float16* wcat = (_Float16*)take((size_t)4 * 6144 * 1024 * 2);   // [Wqkv|Wa|Wg]^T per layer
    _Float16* wo   = (_Float16*)take((size_t)4 * 1024 * 1024 * 2);
    _Float16* w1   = (_Float16*)take((size_t)4 * 4096 * 1024 * 2);
    _Float16* w2   = (_Float16*)take((size_t)4 * 1024 * 4096 * 2);
    // region shared by 4x16MiB scan scratch (layers) and Wl fp16 (62.5MiB, end)
    char*     wlRegion = take((size_t)64 << 20);
    _Float16* wl   = (_Float16*)wlRegion;
    float*    x    = (float*)take((size_t)4096 * 1024 * 4);
    _Float16* xn   = (_Float16*)take((size_t)4096 * 1024 * 2);
    float*    qkvb = (float*)take((size_t)4096 * 3072 * 4);   // 48MiB (also hosts h fp16 33.5MiB)
    float*    alb  = (float*)take((size_t)4096 * 2048 * 4);   // 32MiB (also yT + gated)
    float*    G    = (float*)take((size_t)4096 * 1024 * 4);   // 16MiB

    float* qT   = (float*)wlRegion;
    float* kvT  = (float*)(wlRegion + ((size_t)16 << 20));
    float* aReT = (float*)(wlRegion + ((size_t)32 << 20));
    float* aImT = (float*)(wlRegion + ((size_t)48 << 20));
    float*    yT    = alb;                                           // [0,16MiB)
    _Float16* gated = (_Float16*)((char*)alb + ((size_t)16 << 20));  // 8.4MiB
    _Float16* h     = (_Float16*)qkvb;                               // 33.5MiB

    const dim3 blk(256);

    // weight transposes (f32 [K][N] -> fp16 [N][K])
    transpose_f16_kernel<<<dim3(32,  96, 4), blk, 0, stream>>>(Wqkv, wcat,               1024, 3072, (size_t)6144 * 1024);
    transpose_f16_kernel<<<dim3(32,  64, 4), blk, 0, stream>>>(Wa,   wcat + 3072 * 1024, 1024, 2048, (size_t)6144 * 1024);
    transpose_f16_kernel<<<dim3(32,  32, 4), blk, 0, stream>>>(Wg,   wcat + 5120 * 1024, 1024, 1024, (size_t)6144 * 1024);
    transpose_f16_kernel<<<dim3(32,  32, 4), blk, 0, stream>>>(Wo,   wo,  1024, 1024, (size_t)1024 * 1024);
    transpose_f16_kernel<<<dim3(32, 128, 4), blk, 0, stream>>>(W1,   w1,  1024, 4096, (size_t)4096 * 1024);
    transpose_f16_kernel<<<dim3(128, 32, 4), blk, 0, stream>>>(W2,   w2,  4096, 1024, (size_t)1024 * 4096);

    embed_kernel<<<4096, blk, 0, stream>>>(tokens, emb, x);

    for (int i = 0; i < 4; ++i) {
        rms_f16_kernel<<<4096, blk, 0, stream>>>(x, g1 + i * 1024, xn);
        gemm_kernel<6><<<dim3(32, 48), blk, 0, stream>>>(
            xn, wcat + (size_t)i * 6144 * 1024, ba + i * 2048,
            qkvb, alb, G, nullptr, 4096, 6144, 1024);
        prep_qkv_kernel<<<dim3(64, 32, 2), blk, 0, stream>>>(qkvb, qT, kvT);
        prep_a_kernel<<<dim3(64, 32, 2), blk, 0, stream>>>(alb, aReT, aImT);
        scanT_kernel<<<2048, blk, 0, stream>>>(kvT, aReT, aImT, qT, yT);
        gate_kernel<<<dim3(64, 32, 2), blk, 0, stream>>>(G, yT, gated);
        gemm_kernel<2><<<dim3(32, 8), blk, 0, stream>>>(
            gated, wo + (size_t)i * 1024 * 1024, nullptr,
            x, nullptr, nullptr, nullptr, 4096, 1024, 1024);
        rms_f16_kernel<<<4096, blk, 0, stream>>>(x, g2 + i * 1024, xn);
        gemm_kernel<4><<<dim3(32, 32), blk, 0, stream>>>(
            xn, w1 + (size_t)i * 4096 * 1024, b1 + i * 4096,
            nullptr, nullptr, nullptr, h, 4096, 4096, 1024);
        gemm_kernel<3><<<dim3(32, 8), blk, 0, stream>>>(
            h, w2 + (size_t)i * 1024 * 4096, b2 + i * 1024,
            x, nullptr, nullptr, nullptr, 4096, 1024, 4096);
    }

    // Wl transpose deferred: its region was scan scratch during the layers
    transpose_f16_kernel<<<dim3(32, 1000, 1), blk, 0, stream>>>(Wl, wl, 1024, 32000, 0);

    rms_f16_kernel<<<4096, blk, 0, stream>>>(x, gf, xn);
    gemm_kernel<0><<<dim3(32, 250), blk, 0, stream>>>(
        xn, wl, nullptr, out, nullptr, nullptr, nullptr, 4096, 32000, 1024);
}